// Round 1
// baseline (80877.277 us; speedup 1.0000x reference)
//
#include <hip/hip_runtime.h>
#include <math.h>

// ---- static dims ----
#define B8      8
#define LSEQ    512
#define CDIM    256      // LSTM hidden
#define GDIM    1024     // 4*CDIM
#define WDIM    512      // DNC word len
#define NCELL   32
#define RHEADS  8
#define XI_DIM  10299
#define DOUT    140      // DNC_OUT
#define K_Z0    4492     // 140 + 4096 + 256
#define K_Y     4352     // 256 + 4096
#define HTP     512      // n_pairs
#define RELK    97
#define BI      148      // H + DIS

__device__ __forceinline__ float sigf(float x){
  return (x >= 0.f) ? 1.f/(1.f + expf(-x)) : expf(x)/(1.f + expf(x));
}
__device__ __forceinline__ float spf(float x){ // softplus, stable
  return (x > 0.f) ? x + log1pf(expf(-x)) : log1pf(expf(x));
}

// ---------------------------------------------------------------- sent gather
__global__ __launch_bounds__(256)
void k_sent(const int* __restrict__ cidx, const int* __restrict__ pos,
            const int* __restrict__ ner, const float* __restrict__ wemb,
            const float* __restrict__ eemb, const float* __restrict__ nemb,
            float* __restrict__ sent)
{
  int flat = blockIdx.x*256 + threadIdx.x;
  if (flat >= B8*LSEQ*140) return;
  int d = flat % 140; int bl = flat / 140;
  float v;
  if (d < 100)      v = wemb[(size_t)cidx[bl]*100 + d];
  else if (d < 120) v = eemb[(size_t)pos[bl]*20 + (d-100)];
  else              v = nemb[(size_t)ner[bl]*20 + (d-120)];
  sent[flat] = v;
}

// ------------------------------------------- K1: z0 gemm (+deferred y(t-1))
// z0[s][c] = b0[c] + sum_k ain[s][k]*W[k][c], ain = [sent(t) 140 | reads 4096 | h0 256]
// y wgs: y(t-1)[s][c] = b_out[c] + sum_k [h(t-1) 256 | reads(t-1) 4096][k]*W_out[k][c]
__global__ __launch_bounds__(256)
void k1_z0y(const float* __restrict__ Wih0, const float* __restrict__ Whh0,
            const float* __restrict__ b0,
            const float* __restrict__ Wout, const float* __restrict__ bout,
            const float* __restrict__ sent, const float* __restrict__ reads,
            const float* __restrict__ h0g, const float* __restrict__ Hh,
            float* __restrict__ z0, float* __restrict__ yh, int t, int yonly)
{
  __shared__ float sAin[B8][512];
  __shared__ float sRed[256][33];
  const int tid = threadIdx.x;
  const int wg  = blockIdx.x;
  const bool isY = (yonly != 0) || (wg >= 64);

  if (isY) {
    if (t == 0) return;
    const int yw = yonly ? wg : (wg - 64);
    const int c0 = yw*8;
    const int cq = tid & 1, ks = tid >> 1;       // 128 k-slices, 4 k each/chunk
    float acc[8][4];
    for (int s=0;s<8;s++) for(int e=0;e<4;e++) acc[s][e]=0.f;
    const float* Hrow = Hh + (size_t)(t-1)*B8*CDIM;
    for (int kc = 0; kc < K_Y; kc += 512) {
      int klen = min(512, K_Y - kc);
      for (int ii=0; ii<16; ii++){
        int flat = tid + 256*ii; int s = flat >> 9; int kk = flat & 511;
        int g = kc + kk; float v = 0.f;
        if (kk < klen) v = (g < CDIM) ? Hrow[s*CDIM + g] : reads[s*4096 + (g-CDIM)];
        sAin[s][kk] = v;
      }
      __syncthreads();
      for (int k4=0; k4<4; k4++){
        int kk = ks*4 + k4;
        if (kk < klen) {
          int k = kc + kk;
          const float* wrow = Wout + (size_t)k*DOUT;
          float w[4];
          #pragma unroll
          for (int e=0;e<4;e++){ int c = c0 + cq*4 + e; w[e] = (c < DOUT) ? wrow[c] : 0.f; }
          #pragma unroll
          for (int s=0;s<8;s++){
            float a = sAin[s][kk];
            acc[s][0] += a*w[0]; acc[s][1] += a*w[1];
            acc[s][2] += a*w[2]; acc[s][3] += a*w[3];
          }
        }
      }
      __syncthreads();
    }
    for (int s=0;s<8;s++) for(int e=0;e<4;e++) sRed[tid][s*4+e] = acc[s][e];
    __syncthreads();
    if (tid < 64) {
      int cl = tid & 7, s = tid >> 3;
      int cq2 = (tid >> 2) & 1, ci = tid & 3;
      float sum = 0.f;
      for (int k2=0;k2<128;k2++) sum += sRed[cq2 + 2*k2][s*4+ci];
      int c = c0 + cl;
      if (c < DOUT) yh[((size_t)s*LSEQ + (t-1))*DOUT + c] = sum + bout[c];
    }
    return;
  }

  // ---- Z0 role: wg in [0,64), 16 cols each ----
  const int c0 = wg*16;
  const int cq = tid & 3, ks = tid >> 2;         // 64 k-slices, 8 k each/chunk
  float acc[8][4];
  for (int s=0;s<8;s++) for(int e=0;e<4;e++) acc[s][e]=0.f;
  for (int kc = 0; kc < K_Z0; kc += 512) {
    int klen = min(512, K_Z0 - kc);
    for (int ii=0; ii<16; ii++){
      int flat = tid + 256*ii; int s = flat >> 9; int kk = flat & 511;
      int g = kc + kk; float v = 0.f;
      if (kk < klen) {
        if (g < 140)       v = sent[((size_t)s*LSEQ + t)*140 + g];
        else if (g < 4236) v = reads[s*4096 + (g-140)];
        else               v = h0g[s*CDIM + (g-4236)];
      }
      sAin[s][kk] = v;
    }
    __syncthreads();
    for (int k8=0; k8<8; k8++){
      int kk = ks*8 + k8;
      if (kk < klen) {
        int k = kc + kk;
        const float* wrow = (k < 4236) ? (Wih0 + (size_t)k*GDIM)
                                       : (Whh0 + (size_t)(k-4236)*GDIM);
        float4 w = *reinterpret_cast<const float4*>(wrow + c0 + cq*4);
        #pragma unroll
        for (int s=0;s<8;s++){
          float a = sAin[s][kk];
          acc[s][0] += a*w.x; acc[s][1] += a*w.y; acc[s][2] += a*w.z; acc[s][3] += a*w.w;
        }
      }
    }
    __syncthreads();
  }
  for (int s=0;s<8;s++) for(int e=0;e<4;e++) sRed[tid][s*4+e] = acc[s][e];
  __syncthreads();
  if (tid < 128) {
    int cl = tid & 15, s = tid >> 4;
    int cq2 = (tid >> 2) & 3, ci = tid & 3;
    float sum = 0.f;
    for (int k2=0;k2<64;k2++) sum += sRed[cq2 + 4*k2][s*4+ci];
    int c = c0 + cl;
    z0[s*GDIM + c] = sum + b0[c];
  }
}

// --------------------------- K2/K3: LSTM cell(prev z) + next-layer z gemm
// prologue: h = cell(zin, c[par]) (redundant per wg; wg s writes c[par^1], houtg)
// z[s][c] = bias[c] + sum_{k<256} h[k]*Wa[k][c] + sum_{k<256} hrec[k]*Wb[k][c]
__global__ __launch_bounds__(256)
void k_mid(const float* __restrict__ zin, float* __restrict__ cg, int par,
           float* __restrict__ houtg, const float* __restrict__ hsrc,
           const float* __restrict__ Wa, const float* __restrict__ Wb,
           const float* __restrict__ bias, float* __restrict__ zout)
{
  __shared__ float sAin[B8][512];
  __shared__ float sRed[256][33];
  const int tid = threadIdx.x, wg = blockIdx.x;
  for (int ii=0; ii<8; ii++){
    int cid = tid + 256*ii; int s = cid >> 8; int j = cid & 255;
    float zi = zin[s*GDIM + j],       zf = zin[s*GDIM + 256 + j];
    float zg = zin[s*GDIM + 512 + j], zo = zin[s*GDIM + 768 + j];
    float cold = cg[par*2048 + s*256 + j];
    float cn = sigf(zf)*cold + sigf(zi)*tanhf(zg);
    float h  = sigf(zo)*tanhf(cn);
    sAin[s][j] = h;
    if (wg == s) { cg[(par^1)*2048 + s*256 + j] = cn; houtg[s*256 + j] = h; }
  }
  for (int ii=0; ii<8; ii++){
    int cid = tid + 256*ii; int s = cid >> 8; int j = cid & 255;
    sAin[s][256 + j] = hsrc ? hsrc[s*256 + j] : 0.f;
  }
  __syncthreads();
  const int c0 = wg*16;
  const int cq = tid & 3, ks = tid >> 2;     // 64 slices * 8 k = 512
  float acc[8][4];
  for (int s=0;s<8;s++) for(int e=0;e<4;e++) acc[s][e]=0.f;
  for (int k8=0;k8<8;k8++){
    int k = ks*8 + k8;
    const float* wrow = (k < 256) ? (Wa + (size_t)k*GDIM) : (Wb + (size_t)(k-256)*GDIM);
    float4 w = *reinterpret_cast<const float4*>(wrow + c0 + cq*4);
    #pragma unroll
    for (int s=0;s<8;s++){
      float a = sAin[s][k];
      acc[s][0] += a*w.x; acc[s][1] += a*w.y; acc[s][2] += a*w.z; acc[s][3] += a*w.w;
    }
  }
  for (int s=0;s<8;s++) for(int e=0;e<4;e++) sRed[tid][s*4+e] = acc[s][e];
  __syncthreads();
  if (tid < 128) {
    int cl = tid & 15, s = tid >> 4;
    int cq2 = (tid >> 2) & 3, ci = tid & 3;
    float sum = 0.f;
    for (int k2=0;k2<64;k2++) sum += sRed[cq2 + 4*k2][s*4+ci];
    int c = c0 + cl;
    zout[s*GDIM + c] = sum + bias[c];
  }
}

// --------------------------------- K4: cell2 -> h, H_hist[t]; xi = h @ W_xi
__global__ __launch_bounds__(256)
void k4_xi(const float* __restrict__ z2, float* __restrict__ c2g, int par,
           float* __restrict__ Hh, const float* __restrict__ Wxi,
           const float* __restrict__ bxi, float* __restrict__ xi, int t)
{
  __shared__ float sH[B8][CDIM];
  __shared__ float sRed[256][33];
  const int tid = threadIdx.x, wg = blockIdx.x;
  for (int ii=0; ii<8; ii++){
    int cid = tid + 256*ii; int s = cid >> 8; int j = cid & 255;
    float zi = z2[s*GDIM + j],       zf = z2[s*GDIM + 256 + j];
    float zg = z2[s*GDIM + 512 + j], zo = z2[s*GDIM + 768 + j];
    float cold = c2g[par*2048 + s*256 + j];
    float cn = sigf(zf)*cold + sigf(zi)*tanhf(zg);
    float h  = sigf(zo)*tanhf(cn);
    h = fminf(fmaxf(h, -20.f), 20.f);     // clip (identity in range, kept for parity)
    sH[s][j] = h;
    if (wg == s) { c2g[(par^1)*2048 + s*256 + j] = cn; Hh[((size_t)t*B8 + s)*CDIM + j] = h; }
  }
  __syncthreads();
  const int c0 = wg*64;
  const int cq = tid & 15, ks = tid >> 4;   // 16 slices * 16 k = 256
  float acc[8][4];
  for (int s=0;s<8;s++) for(int e=0;e<4;e++) acc[s][e]=0.f;
  for (int k16=0;k16<16;k16++){
    int k = ks*16 + k16;
    const float* wrow = Wxi + (size_t)k*XI_DIM;
    float w[4];
    #pragma unroll
    for (int e=0;e<4;e++){ int c = c0 + cq*4 + e; w[e] = (c < XI_DIM) ? wrow[c] : 0.f; }
    #pragma unroll
    for (int s=0;s<8;s++){
      float a = sH[s][k];
      acc[s][0] += a*w[0]; acc[s][1] += a*w[1]; acc[s][2] += a*w[2]; acc[s][3] += a*w[3];
    }
  }
  for (int s=0;s<8;s++) for(int e=0;e<4;e++) sRed[tid][s*4+e] = acc[s][e];
  __syncthreads();
  for (int o = tid; o < 512; o += 256){
    int cq2 = (o >> 2) & 15, ci = o & 3, s = o >> 6;
    float sum = 0.f;
    for (int k2=0;k2<16;k2++) sum += sRed[cq2 + 16*k2][s*4+ci];
    int c = c0 + (o & 63);
    if (c < XI_DIM) xi[(size_t)s*XI_DIM + c] = sum + bxi[c];
  }
}

// -------------------------------------- K5: per-sample DNC memory addressing
__global__ __launch_bounds__(512)
void k5_mem(const float* __restrict__ xi_g, float* __restrict__ M_g,
            float* __restrict__ u_g, float* __restrict__ ww_g, float* __restrict__ p_g,
            float* __restrict__ wr_g, float* __restrict__ L_g,
            float* __restrict__ reads_g)
{
  const int s = blockIdx.x;
  const int tid = threadIdx.x;
  const float* xi = xi_g + (size_t)s*XI_DIM;
  float* M = M_g + (size_t)s*NCELL*WDIM;

  __shared__ float s_rk[RHEADS][WDIM], s_rm[RHEADS][WDIM];
  __shared__ float s_wk[WDIM], s_wm[WDIM], s_er[WDIM], s_wv[WDIM];
  __shared__ float s_L[NCELL][NCELL];
  __shared__ float s_wr[RHEADS][NCELL], s_wrn[RHEADS][NCELL], s_cr[RHEADS][NCELL];
  __shared__ float s_fw[RHEADS][NCELL], s_bw[RHEADS][NCELL];
  __shared__ float s_psi[NCELL], s_u[NCELL], s_us[NCELL], s_a[NCELL], s_cw[NCELL];
  __shared__ float s_wwn[NCELL], s_wwo[NCELL], s_p[NCELL];
  __shared__ int   s_ord[NCELL];
  __shared__ float s_rb[RHEADS], s_sf[RHEADS], s_sb[RHEADS], s_fg[RHEADS], s_kn[RHEADS];
  __shared__ float s_pi[RHEADS][3];
  __shared__ float s_sc[64];

  // ---- phase 0: load + transform interface vector, load state ----
  for (int ii=0; ii<8; ii++){
    int f = tid + 512*ii; int r = f >> 9, w = f & 511;
    s_rk[r][w] = xi[f];
    s_rm[r][w] = 0.1f + 0.9f*sigf(xi[6187 + f]);
  }
  s_wk[tid] = xi[4104 + tid];
  s_er[tid] = sigf(xi[4617 + tid]);
  s_wv[tid] = xi[5129 + tid];
  s_wm[tid] = 0.1f + 0.9f*sigf(xi[5675 + tid]);
  if (tid < RHEADS){
    s_rb[tid] = 1.f + spf(xi[4096 + tid]);
    s_fg[tid] = sigf(xi[5641 + tid]);
    s_sf[tid] = 1.f + spf(xi[10283 + tid]);
    s_sb[tid] = 1.f + spf(xi[10291 + tid]);
    float e0 = xi[5651+3*tid], e1 = xi[5651+3*tid+1], e2 = xi[5651+3*tid+2];
    float mx = fmaxf(e0, fmaxf(e1, e2));
    float x0 = expf(e0-mx), x1 = expf(e1-mx), x2 = expf(e2-mx);
    float inv = 1.f/(x0+x1+x2);
    s_pi[tid][0]=x0*inv; s_pi[tid][1]=x1*inv; s_pi[tid][2]=x2*inv;
  }
  if (tid == 0){
    s_sc[0] = 1.f + spf(xi[4616]);  // wb
    s_sc[1] = sigf(xi[5649]);       // ga
    s_sc[2] = sigf(xi[5650]);       // gw
  }
  if (tid < NCELL){
    s_u[tid]   = u_g[s*NCELL + tid];
    s_wwo[tid] = ww_g[s*NCELL + tid];
    s_p[tid]   = p_g[s*NCELL + tid];
  }
  if (tid < 256) s_wr[tid>>5][tid&31] = wr_g[s*256 + tid];
  for (int ii=0; ii<2; ii++){ int f = tid + 512*ii; s_L[f>>5][f&31] = L_g[s*1024 + f]; }
  __syncthreads();

  // ---- phase 1+2: psi, usage ----
  if (tid < NCELL){
    float psi = 1.f;
    #pragma unroll
    for (int r=0;r<8;r++) psi *= (1.f - s_fg[r]*s_wr[r][tid]);
    s_psi[tid] = psi;
    float uo = s_u[tid], wo = s_wwo[tid];
    s_u[tid] = (uo + wo - uo*wo)*psi;
  }
  __syncthreads();

  // ---- phase 3: stable ascending argsort of u (N=32) ----
  if (tid < NCELL){
    float un = s_u[tid]; int rank = 0;
    for (int m=0;m<NCELL;m++){
      float um = s_u[m];
      rank += (um < un) || (um == un && m < tid);
    }
    s_ord[rank] = tid;
  }
  __syncthreads();
  if (tid < NCELL) s_us[tid] = s_u[s_ord[tid]];
  __syncthreads();
  if (tid == 0){
    float cp = 1.f;
    for (int j=0;j<NCELL;j++){ s_a[s_ord[j]] = (1.f - s_us[j])*cp; cp *= s_us[j]; }
  }
  __syncthreads();

  // ---- phase 5: write content weighting cw (over OLD M) ----
  {
    float v = s_wk[tid]*s_wm[tid];
    float q = v*v;
    for (int o=32;o;o>>=1) q += __shfl_down(q, o, 64);
    if ((tid & 63) == 0) s_sc[8 + (tid >> 6)] = q;
  }
  __syncthreads();
  if (tid == 0){ float q=0; for(int i=0;i<8;i++) q += s_sc[8+i]; s_sc[3] = sqrtf(q); }
  __syncthreads();
  {
    int n = tid >> 4, wsub = tid & 15;
    float d=0.f, q=0.f;
    for (int i=0;i<32;i++){
      int w = wsub + 16*i;
      float m = M[(size_t)n*WDIM + w]; float wm = s_wm[w];
      d += s_wk[w]*wm*wm*m; float t2 = m*wm; q += t2*t2;
    }
    for (int o=8;o;o>>=1){ d += __shfl_down(d,o,16); q += __shfl_down(q,o,16); }
    if (wsub == 0){
      float cs = d/(s_sc[3]*sqrtf(q) + 1e-6f);
      s_cw[n] = s_sc[0]*cs;          // logits = wb*cos
    }
  }
  __syncthreads();
  if (tid == 0){ float mx=-1e30f; for(int n=0;n<32;n++) mx = fmaxf(mx, s_cw[n]); s_sc[4]=mx; }
  __syncthreads();
  if (tid < NCELL) s_cw[tid] = expf(s_cw[tid] - s_sc[4]);
  __syncthreads();
  if (tid == 0){ float sm=0; for(int n=0;n<32;n++) sm += s_cw[n]; s_sc[5] = 1.f/sm; }
  __syncthreads();
  if (tid < NCELL) s_cw[tid] *= s_sc[5];
  __syncthreads();

  // ---- phase 6: write weights ----
  if (tid < NCELL) s_wwn[tid] = s_sc[2]*( s_sc[1]*s_a[tid] + (1.f - s_sc[1])*s_cw[tid] );
  __syncthreads();

  // ---- phase 7: M dealloc + erase/write ----
  for (int ii=0; ii<32; ii++){
    int f = tid + 512*ii; int n = f >> 9, w = f & 511;
    size_t idx = (size_t)n*WDIM + w;
    float m = M[idx];
    m = m*s_psi[n]*(1.f - s_wwn[n]*s_er[w]) + s_wwn[n]*s_wv[w];
    M[idx] = m;
  }
  __syncthreads();

  // ---- phase 8: link matrix (uses OLD p), then precedence ----
  for (int ii=0; ii<2; ii++){
    int f = tid + 512*ii; int i = f >> 5, j = f & 31;
    float nl = (1.f - s_wwn[i] - s_wwn[j])*s_L[i][j] + s_wwn[i]*s_p[j];
    s_L[i][j] = (i == j) ? 0.f : nl;
  }
  __syncthreads();
  if (tid == 0){ float sw=0; for(int n=0;n<32;n++) sw += s_wwn[n]; s_sc[6]=sw; }
  __syncthreads();
  if (tid < NCELL) s_p[tid] = (1.f - s_sc[6])*s_p[tid] + s_wwn[tid];
  __syncthreads();

  // ---- phase 9: fw/bw (sharpened), uses OLD wr ----
  {
    int r = (tid >> 5) & 7, i = tid & 31; bool isB = (tid >= 256);
    float accv = 0.f;
    if (!isB){ for (int j=0;j<32;j++) accv += s_L[i][j]*s_wr[r][j]; }
    else     { for (int j=0;j<32;j++) accv += s_L[j][i]*s_wr[r][j]; }
    float sp = isB ? s_sb[r] : s_sf[r];
    float e = expf(sp*logf(accv + 1e-6f));
    if (!isB) s_fw[r][i] = e; else s_bw[r][i] = e;
  }
  __syncthreads();
  if (tid < 16){
    int r = tid & 7; float sm = 0.f;
    if (tid < 8){ for (int n=0;n<32;n++) sm += s_fw[r][n]; s_sc[16+r] = 1.f/sm; }
    else        { for (int n=0;n<32;n++) sm += s_bw[r][n]; s_sc[24+r] = 1.f/sm; }
  }
  __syncthreads();
  {
    int r = (tid >> 5) & 7, i = tid & 31; bool isB = (tid >= 256);
    if (!isB) s_fw[r][i] *= s_sc[16+r]; else s_bw[r][i] *= s_sc[24+r];
  }
  __syncthreads();

  // ---- phase 10: read content weighting cr (NEW M) ----
  {
    int r = tid >> 6, wsub = tid & 63;
    float q = 0.f;
    for (int i2=0;i2<8;i2++){ int w = wsub + 64*i2; float v = s_rk[r][w]*s_rm[r][w]; q += v*v; }
    for (int o=32;o;o>>=1) q += __shfl_down(q, o, 64);
    if (wsub == 0) s_kn[r] = sqrtf(q);
  }
  __syncthreads();
  {
    int r = tid >> 6, rem = tid & 63, n = rem >> 1, h = rem & 1;
    float d=0.f, q=0.f;
    for (int i2=0;i2<256;i2++){
      int w = h*256 + i2;
      float m = M[(size_t)n*WDIM + w]; float rm = s_rm[r][w];
      d += s_rk[r][w]*rm*rm*m; float t2 = m*rm; q += t2*t2;
    }
    d += __shfl_down(d,1,2); q += __shfl_down(q,1,2);
    if (h == 0){
      float cs = d/(s_kn[r]*sqrtf(q) + 1e-6f);
      s_cr[r][n] = s_rb[r]*cs;     // logits
    }
  }
  __syncthreads();
  if (tid < 8){
    int r = tid; float mx = -1e30f;
    for (int n=0;n<32;n++) mx = fmaxf(mx, s_cr[r][n]);
    float sm = 0.f;
    for (int n=0;n<32;n++){ float e = expf(s_cr[r][n]-mx); s_cr[r][n] = e; sm += e; }
    float inv = 1.f/sm;
    for (int n=0;n<32;n++) s_cr[r][n] *= inv;
  }
  __syncthreads();

  // ---- phase 11: new read weights ----
  if (tid < 256){
    int r = tid >> 5, n = tid & 31;
    float v = s_pi[r][0]*s_bw[r][n] + s_pi[r][1]*s_cr[r][n] + s_pi[r][2]*s_fw[r][n];
    s_wrn[r][n] = v; wr_g[s*256 + tid] = v;
  }
  __syncthreads();

  // ---- phase 12: reads = wr_new @ M_new ----
  {
    int r = tid >> 6, wsub = tid & 63;
    for (int i2=0;i2<8;i2++){
      int w = wsub + 64*i2;
      float accv = 0.f;
      for (int n=0;n<32;n++) accv += s_wrn[r][n]*M[(size_t)n*WDIM + w];
      reads_g[s*4096 + r*512 + w] = accv;
    }
  }
  // ---- phase 13: state writeback ----
  if (tid < NCELL){
    u_g[s*NCELL + tid] = s_u[tid];
    ww_g[s*NCELL + tid] = s_wwn[tid];
    p_g[s*NCELL + tid] = s_p[tid];
  }
  for (int ii=0; ii<2; ii++){ int f = tid + 512*ii; L_g[s*1024 + f] = s_L[f>>5][f&31]; }
}

// ---------------------------------------- generic 16-row tiled gemm (lda==K)
__global__ __launch_bounds__(256)
void gemm16(int M, int N, int K,
            const float* __restrict__ A, long long sAb, int lda,
            const float* __restrict__ Bm, long long sBb, int ldb,
            float* __restrict__ C, long long sCb, int ldc,
            const float* __restrict__ bias, int relu)
{
  __shared__ float sA[16*512];
  const int tid = threadIdx.x;
  const float* Ab = A + (size_t)blockIdx.y*sAb;
  const float* Bb = Bm + (size_t)blockIdx.y*sBb;
  float* Cb = C + (size_t)blockIdx.y*sCb;
  const int m0 = blockIdx.x*16;
  const int tot = 16*K;
  for (int f = tid; f < tot; f += 256) sA[f] = Ab[(size_t)m0*lda + f]; // lda==K
  __syncthreads();
  int c = (tid & 63)*4; int rg = tid >> 6;
  if (c >= N) return;
  float acc[4][4] = {};
  for (int k=0;k<K;k++){
    float4 bv = *reinterpret_cast<const float4*>(Bb + (size_t)k*ldb + c);
    #pragma unroll
    for (int rr=0;rr<4;rr++){
      float a = sA[(rg*4+rr)*K + k];
      acc[rr][0] += a*bv.x; acc[rr][1] += a*bv.y; acc[rr][2] += a*bv.z; acc[rr][3] += a*bv.w;
    }
  }
  for (int rr=0;rr<4;rr++){
    int m = m0 + rg*4 + rr;
    #pragma unroll
    for (int e=0;e<4;e++){
      float v = acc[rr][e] + (bias ? bias[c+e] : 0.f);
      if (relu) v = fmaxf(v, 0.f);
      Cb[(size_t)m*ldc + c + e] = v;
    }
  }
}

// ------------------------------------------------------------ bilinear head
__global__ __launch_bounds__(256)
void bilin(const float* __restrict__ s0, const float* __restrict__ t0,
           const float* __restrict__ dis_emb, const int* __restrict__ dht,
           const int* __restrict__ dth, const float* __restrict__ Wb,
           const float* __restrict__ bb, float* __restrict__ out)
{
  __shared__ float sS[BI][33];    // s_rep transposed [i][pp]
  __shared__ float sT[32][152];   // t_rep [pp][i]
  const int tid = threadIdx.x;
  const int bp0 = blockIdx.x*32;
  for (int f = tid; f < 32*BI; f += 256){
    int pp = f / BI, i = f % BI;
    int bp = bp0 + pp;
    float sv, tv;
    if (i < 128){ sv = s0[(size_t)bp*128 + i]; tv = t0[(size_t)bp*128 + i]; }
    else {
      sv = dis_emb[(size_t)dht[bp]*20 + (i-128)];
      tv = dis_emb[(size_t)dth[bp]*20 + (i-128)];
    }
    sS[i][pp] = sv; sT[pp][i] = tv;
  }
  __syncthreads();
  const int ppg = tid >> 5, jb = tid & 31;
  const int pp0 = ppg*4;
  const int k0 = blockIdx.y*49, kend = min(k0+49, RELK);
  for (int k = k0; k < kend; k++){
    const float* Wk = Wb + (size_t)k*BI*BI;
    float acc[4][5];
    #pragma unroll
    for (int a=0;a<4;a++) for (int b=0;b<5;b++) acc[a][b]=0.f;
    for (int i=0;i<BI;i++){
      float sv0 = sS[i][pp0], sv1 = sS[i][pp0+1], sv2 = sS[i][pp0+2], sv3 = sS[i][pp0+3];
      const float* wrow = Wk + i*BI;
      #pragma unroll
      for (int jj=0;jj<5;jj++){
        int j = jb + 32*jj;
        if (j < BI){
          float w = wrow[j];
          acc[0][jj] += sv0*w; acc[1][jj] += sv1*w; acc[2][jj] += sv2*w; acc[3][jj] += sv3*w;
        }
      }
    }
    float dot[4] = {0.f,0.f,0.f,0.f};
    #pragma unroll
    for (int jj=0;jj<5;jj++){
      int j = jb + 32*jj;
      if (j < BI){
        #pragma unroll
        for (int p4=0;p4<4;p4++) dot[p4] += acc[p4][jj]*sT[pp0+p4][j];
      }
    }
    #pragma unroll
    for (int p4=0;p4<4;p4++)
      for (int o=16;o;o>>=1) dot[p4] += __shfl_down(dot[p4], o, 32);
    if (jb == 0){
      #pragma unroll
      for (int p4=0;p4<4;p4++)
        out[(size_t)(bp0+pp0+p4)*RELK + k] = dot[p4] + bb[k];
    }
  }
}

// =========================================================== host launcher
extern "C" void kernel_launch(void* const* d_in, const int* in_sizes, int n_in,
                              void* d_out, int out_size, void* d_ws, size_t ws_size,
                              hipStream_t stream)
{
  (void)in_sizes; (void)n_in; (void)out_size; (void)ws_size;
  const int*   ctx_idx = (const int*)  d_in[0];
  const int*   pos     = (const int*)  d_in[1];
  const int*   nerI    = (const int*)  d_in[2];
  const float* h_map   = (const float*)d_in[5];
  const float* t_map   = (const float*)d_in[6];
  const int*   dht     = (const int*)  d_in[8];
  const int*   dth     = (const int*)  d_in[9];
  const float* wemb    = (const float*)d_in[10];
  const float* eemb    = (const float*)d_in[11];
  const float* nemb    = (const float*)d_in[12];
  const float* demb    = (const float*)d_in[13];
  const float* Wih0    = (const float*)d_in[14];
  const float* Whh0    = (const float*)d_in[15];
  const float* b0      = (const float*)d_in[16];
  const float* Wih1    = (const float*)d_in[17];
  const float* Whh1    = (const float*)d_in[18];
  const float* b1      = (const float*)d_in[19];
  const float* Wih2    = (const float*)d_in[20];
  const float* Whh2    = (const float*)d_in[21];
  const float* b2      = (const float*)d_in[22];
  const float* Wxi     = (const float*)d_in[23];
  const float* bxi     = (const float*)d_in[24];
  const float* Wout    = (const float*)d_in[25];
  const float* bout    = (const float*)d_in[26];
  const float* Wfin    = (const float*)d_in[27];
  const float* bfin    = (const float*)d_in[28];
  const float* Wre     = (const float*)d_in[29];
  const float* bre     = (const float*)d_in[30];
  const float* Wbili   = (const float*)d_in[31];
  const float* bbili   = (const float*)d_in[32];

  float* ws   = (float*)d_ws;
  float* sent = ws;                        // [8][512][140]
  float* Hh   = sent + 573440;             // [512][8][256]
  float* yh   = Hh + 1048576;              // [8][512][140]
  float* o256 = yh + 573440;               // [8*512][256]
  float* ctxb = o256 + 1048576;            // [8*512][128]
  float* s0b  = ctxb + 524288;             // [8*512][128]
  float* t0b  = s0b + 524288;              // [8*512][128]
  float* stateBase = t0b + 524288;
  float* reads = stateBase;                // [8][4096]
  float* h0g   = reads + 32768;            // [8][256]
  float* h1g   = h0g + 2048;               // [8][256]
  float* c0g   = h1g + 2048;               // [2][8][256]
  float* c1g   = c0g + 4096;
  float* c2g   = c1g + 4096;
  float* z0    = c2g + 4096;               // [8][1024]
  float* z1    = z0 + 8192;
  float* z2    = z1 + 8192;
  float* xib   = z2 + 8192;                // [8][10299]
  float* Mb    = xib + 82392;              // [8][32][512]
  float* ug    = Mb + 131072;              // [8][32]
  float* wwg   = ug + 256;
  float* pg    = wwg + 256;
  float* wrg   = pg + 256;                 // [8][8][32]
  float* Lg    = wrg + 2048;               // [8][32][32]
  float* stateEnd = Lg + 8192;
  size_t stateBytes = (size_t)(stateEnd - stateBase)*sizeof(float);
  hipMemsetAsync(stateBase, 0, stateBytes, stream);

  hipLaunchKernelGGL(k_sent, dim3((573440+255)/256), dim3(256), 0, stream,
                     ctx_idx, pos, nerI, wemb, eemb, nemb, sent);

  for (int t = 0; t < LSEQ; t++){
    int par = t & 1;
    hipLaunchKernelGGL(k1_z0y, dim3(82), dim3(256), 0, stream,
                       Wih0, Whh0, b0, Wout, bout, sent, reads, h0g, Hh, z0, yh, t, 0);
    hipLaunchKernelGGL(k_mid, dim3(64), dim3(256), 0, stream,
                       z0, c0g, par, h0g, h1g, Wih1, Whh1, b1, z1);
    hipLaunchKernelGGL(k_mid, dim3(64), dim3(256), 0, stream,
                       z1, c1g, par, h1g, (t > 0) ? (Hh + (size_t)(t-1)*2048) : (const float*)nullptr,
                       Wih2, Whh2, b2, z2);
    hipLaunchKernelGGL(k4_xi, dim3(161), dim3(256), 0, stream,
                       z2, c2g, par, Hh, Wxi, bxi, xib, t);
    hipLaunchKernelGGL(k5_mem, dim3(8), dim3(512), 0, stream,
                       xib, Mb, ug, wwg, pg, wrg, Lg, reads);
  }
  // final y(511)
  hipLaunchKernelGGL(k1_z0y, dim3(18), dim3(256), 0, stream,
                     Wih0, Whh0, b0, Wout, bout, sent, reads, h0g, Hh, z0, yh, LSEQ, 1);

  // out = ys @ W_final + b_final          [4096,140]x[140,256]
  hipLaunchKernelGGL(gemm16, dim3(256,1), dim3(256), 0, stream,
                     4096, 256, 140, yh, (long long)0, 140, Wfin, (long long)0, 256,
                     o256, (long long)0, 256, bfin, 0);
  // ctx = relu(out @ W_re + b_re)         [4096,256]x[256,128]
  hipLaunchKernelGGL(gemm16, dim3(256,1), dim3(256), 0, stream,
                     4096, 128, 256, o256, (long long)0, 256, Wre, (long long)0, 128,
                     ctxb, (long long)0, 128, bre, 1);
  // s0 / t0 : per-batch [512,512]x[512,128]
  hipLaunchKernelGGL(gemm16, dim3(32,8), dim3(256), 0, stream,
                     512, 128, 512, h_map, (long long)(512*512), 512,
                     ctxb, (long long)(512*128), 128,
                     s0b, (long long)(512*128), 128, (const float*)nullptr, 0);
  hipLaunchKernelGGL(gemm16, dim3(32,8), dim3(256), 0, stream,
                     512, 128, 512, t_map, (long long)(512*512), 512,
                     ctxb, (long long)(512*128), 128,
                     t0b, (long long)(512*128), 128, (const float*)nullptr, 0);
  // bilinear head
  hipLaunchKernelGGL(bilin, dim3(128,2), dim3(256), 0, stream,
                     s0b, t0b, demb, dht, dth, Wbili, bbili, (float*)d_out);
}